// Round 9
// baseline (279.900 us; speedup 1.0000x reference)
//
#include <hip/hip_runtime.h>

// MultiBoxLoss, 2-dispatch pipeline.
// R7 -> R8: (a) match hot loop tiled 4 priors-in-registers per truth-read:
// LDS reads /4 (was 2 ds_reads per PAIR, now per 4 pairs) to attack the
// latency-bound 40% idle (R7: VALUBusy fell 66->60% while dur only -15%).
// (b) 4 dispatches -> 2: atomicMax replaced by per-block key slots (plain
// stores, no init needed, 0xAA-poison immune); fixup+finalize merged into a
// single-block epilogue. R6/R7 residual (total - kernels) was ~85us across 4
// dispatches -> predicted ~20us/dispatch gap; this tests and harvests it.
//
//   K1 match_loss: per (b,p): 20 IoUs once -> pre-fixup conf -> focal+sl1+npos
//                  block-reduced into part[blockIdx]; per-truth best key
//                  (iou_bits<<32|~p) block-reduced -> pb_keys[block][o].
//   K2 epilogue  : reduce keys over 8 chunks/image -> best prior per truth;
//                  dedup (last-wins); delta-correct losses for <=20 overridden
//                  priors/image; reduce 1024 partials + deltas -> out[0..1].

#define NB 128
#define NP 24564
#define NO 20

#define TILE 4
#define NTILE 3
#define IPT1 (TILE * NTILE)          // 12 priors per thread
#define NCH1 8                       // 8 chunks * 3072 = 24576 >= 24564
#define CHUNK (256 * IPT1)           // 3072
#define NBLK1 (NB * NCH1)            // 1024 match blocks

// ws layout (bytes); all regions fully overwritten every launch
#define KEY_OFF 0                                   // NBLK1*NO u64 = 163840
#define PL_OFF  ((size_t)NBLK1 * NO * 8)
#define PN_OFF  (PL_OFF + (size_t)NBLK1 * 8)

__device__ __forceinline__ float fast_rcp(float x) {
    return __builtin_amdgcn_rcpf(x);               // v_rcp_f32, ~1-2 ulp
}

__device__ __forceinline__ float focal_term(float2 cd, int conf) {
    float mx = fmaxf(cd.x, cd.y);
    float e0 = __expf(cd.x - mx), e1 = __expf(cd.y - mx);
    if (conf > 1) return 0.0f;                     // one_hot(conf>=2,2) == 0
    float pc = ((conf == 0) ? e0 : e1) * fast_rcp(e0 + e1);
    pc = fminf(fmaxf(pc, 1e-7f), 1.0f - 1e-7f);
    float om = 1.0f - pc;
    return 0.25f * (-__logf(pc)) * om * om;
}

__device__ __forceinline__ float sl1_term(float4 m, float4 pr, float4 ld) {
    float gx = ((m.x + m.z) * 0.5f - pr.x) / (0.1f * pr.z);
    float gy = ((m.y + m.w) * 0.5f - pr.y) / (0.1f * pr.w);
    float gw = logf((m.z - m.x) / pr.z) / 0.2f;
    float gh = logf((m.w - m.y) / pr.w) / 0.2f;
    float d0 = ld.x - gx, d1 = ld.y - gy, d2 = ld.z - gw, d3 = ld.w - gh;
    float a0 = fabsf(d0), a1 = fabsf(d1), a2 = fabsf(d2), a3 = fabsf(d3);
    float r = (a0 < 1.0f) ? 0.5f * d0 * d0 : a0 - 0.5f;
    r += (a1 < 1.0f) ? 0.5f * d1 * d1 : a1 - 0.5f;
    r += (a2 < 1.0f) ? 0.5f * d2 * d2 : a2 - 0.5f;
    r += (a3 < 1.0f) ? 0.5f * d3 * d3 : a3 - 0.5f;
    return r;
}

__global__ __launch_bounds__(256) void match_loss_kernel(
    const float4* __restrict__ loc_data,   // [B,P,4]
    const float2* __restrict__ conf_data,  // [B,P,2]
    const float4* __restrict__ priors,     // [P,4] center-form
    const float* __restrict__ bbox,        // [B,O,5]
    unsigned long long* __restrict__ pb_keys,   // [NBLK1][NO]
    float2* __restrict__ part_loss,             // [NBLK1]
    unsigned int* __restrict__ part_np)         // [NBLK1]
{
    const int img  = blockIdx.x / NCH1;
    const int base = (blockIdx.x % NCH1) * CHUNK;
    const int tid  = threadIdx.x;

    __shared__ float4 s_truth[NO];
    __shared__ float  s_area[NO];
    __shared__ int    s_label[NO];
    __shared__ unsigned long long s_keys[4][NO];

    if (tid < NO) {
        const float* t = bbox + ((size_t)img * NO + tid) * 5;
        float4 tb = make_float4(t[0], t[1], t[2], t[3]);
        s_truth[tid] = tb;
        s_area[tid]  = (tb.z - tb.x) * (tb.w - tb.y);
        s_label[tid] = (int)t[4];
    }
    __syncthreads();

    // per-truth running max (iou, k). strict > keeps smallest k on ties ->
    // smallest p within a thread (first-occurrence, p = base + k*256 + tid).
    float bf[NO];
    int   bk[NO];
#pragma unroll
    for (int o = 0; o < NO; ++o) { bf[o] = -1.0f; bk[o] = 0; }

    float lossl = 0.0f, lossc = 0.0f;
    int np = 0;

    for (int t = 0; t < NTILE; ++t) {
        // 4 priors in registers; OOB -> empty far box (iou==0, never beats a
        // valid pair: valid iou>=0 occurs first at k=0 and ties keep first).
        float qx0[TILE], qy0[TILE], qx1[TILE], qy1[TILE], qa[TILE];
        float bv[TILE];
        int   bj[TILE];
#pragma unroll
        for (int j = 0; j < TILE; ++j) {
            const int p = base + (t * TILE + j) * 256 + tid;
            const bool valid = (p < NP);
            float4 pr = priors[valid ? p : (NP - 1)];
            float x0 = pr.x - pr.z * 0.5f, y0 = pr.y - pr.w * 0.5f;
            float x1 = pr.x + pr.z * 0.5f, y1 = pr.y + pr.w * 0.5f;
            qx0[j] = valid ? x0 : 3.0e18f;
            qy0[j] = valid ? y0 : 3.0e18f;
            qx1[j] = valid ? x1 : 3.0e18f;
            qy1[j] = valid ? y1 : 3.0e18f;
            qa[j]  = valid ? (x1 - x0) * (y1 - y0) : 0.0f;
            bv[j] = -1.0f;
            bj[j] = 0;
        }

#pragma unroll
        for (int o = 0; o < NO; ++o) {      // 2 LDS reads shared by 4 pairs
            const float4 tb = s_truth[o];
            const float  ta = s_area[o];
#pragma unroll
            for (int j = 0; j < TILE; ++j) {
                float lx = fmaxf(tb.x, qx0[j]), ly = fmaxf(tb.y, qy0[j]);
                float rx = fminf(tb.z, qx1[j]), ry = fminf(tb.w, qy1[j]);
                float w = fmaxf(rx - lx, 0.0f);
                float h = fmaxf(ry - ly, 0.0f);
                float inter = w * h;
                float iou = inter * fast_rcp(ta + qa[j] - inter);
                if (iou > bf[o]) { bf[o] = iou; bk[o] = t * TILE + j; }
                if (iou > bv[j]) { bv[j] = iou; bj[j] = o; }
            }
        }

        // pre-fixup losses for this tile (epilogue corrects <=20 priors/img)
#pragma unroll
        for (int j = 0; j < TILE; ++j) {
            const int p = base + (t * TILE + j) * 256 + tid;
            if (p >= NP) continue;
            const int conf = (bv[j] >= 0.5f) ? (s_label[bj[j]] + 1) : 0;
            if (conf > 0) {
                np++;
                float4 pr = priors[p];          // rare path, reload (L1-hot)
                lossl += sl1_term(s_truth[bj[j]], pr,
                                  loc_data[(size_t)img * NP + p]);
            }
            lossc += focal_term(conf_data[(size_t)img * NP + p], conf);
        }
    }

    // per-truth keys: butterfly per wave -> LDS -> block max -> plain store
#pragma unroll
    for (int o = 0; o < NO; ++o) {
        const int p = base + bk[o] * 256 + tid;
        unsigned long long v = ((unsigned long long)__float_as_uint(bf[o]) << 32)
                             | (unsigned long long)(0xFFFFFFFFu - (unsigned)p);
#pragma unroll
        for (int s = 32; s > 0; s >>= 1) {
            unsigned long long u = __shfl_xor(v, s, 64);
            v = (v > u) ? v : u;
        }
        if ((tid & 63) == 0) s_keys[tid >> 6][o] = v;
    }

    // loss block reduce -> private partial slot
#pragma unroll
    for (int s = 32; s > 0; s >>= 1) {
        lossl += __shfl_xor(lossl, s, 64);
        lossc += __shfl_xor(lossc, s, 64);
        np    += __shfl_xor(np, s, 64);
    }
    __shared__ float s_ll[4], s_lc[4];
    __shared__ int s_np4[4];
    const int wid = tid >> 6;
    if ((tid & 63) == 0) { s_ll[wid] = lossl; s_lc[wid] = lossc; s_np4[wid] = np; }
    __syncthreads();

    if (tid < NO) {
        unsigned long long m = s_keys[0][tid];
        for (int w = 1; w < 4; ++w) {
            unsigned long long u = s_keys[w][tid];
            m = (m > u) ? m : u;
        }
        pb_keys[(size_t)blockIdx.x * NO + tid] = m;
    }
    if (tid == 0) {
        float tl = 0.0f, tc = 0.0f;
        int tn = 0;
        for (int w = 0; w < 4; ++w) { tl += s_ll[w]; tc += s_lc[w]; tn += s_np4[w]; }
        part_loss[blockIdx.x] = make_float2(tl, tc);
        part_np[blockIdx.x]   = (unsigned int)tn;
    }
}

// Single block: key reduce + dedup + delta corrections + final reduction.
#define TRS 101   // padded truth stride (floats): bank stride 5 -> 2 lanes/bank (free)

__global__ __launch_bounds__(256) void epilogue_kernel(
    const float4* __restrict__ loc_data,
    const float2* __restrict__ conf_data,
    const float4* __restrict__ priors,
    const float* __restrict__ bbox,
    const unsigned long long* __restrict__ pb_keys,
    const float2* __restrict__ part_loss,
    const unsigned int* __restrict__ part_np,
    float* __restrict__ out)
{
    const int tid = threadIdx.x;
    __shared__ float s_tr[NB * TRS];      // 51.7 KB padded truths
    __shared__ int   s_bp[NB][NO];        // 10.2 KB best prior per (img,o)

    // stage all truths (coalesced-ish)
    for (int i = tid; i < NB * NO * 5; i += 256) {
        const int img = i / (NO * 5), f = i % (NO * 5);
        s_tr[img * TRS + f] = bbox[i];
    }
    // best prior per (img,o): max over the image's 8 chunk keys
    for (int u = tid; u < NB * NO; u += 256) {
        const int img = u / NO, o = u - img * NO;
        unsigned long long m = 0ull;
        for (int c = 0; c < NCH1; ++c) {
            unsigned long long v = pb_keys[((size_t)(img * NCH1 + c)) * NO + o];
            m = (m > v) ? m : v;
        }
        s_bp[img][o] = (int)(0xFFFFFFFFu - (unsigned)(m & 0xFFFFFFFFull));
    }
    __syncthreads();

    // per-image delta corrections (one image per lane, 128 active)
    float dll = 0.0f, dlc = 0.0f;
    int dnp = 0;
    if (tid < NB) {
        const int img = tid;
        for (int o = 0; o < NO; ++o) {
            const int bp = s_bp[img][o];
            bool win = true;                       // last-wins on duplicates
            for (int o2 = o + 1; o2 < NO; ++o2) win = win && (s_bp[img][o2] != bp);
            if (!win) continue;

            float4 pr = priors[bp];
            const float px0 = pr.x - pr.z * 0.5f, py0 = pr.y - pr.w * 0.5f;
            const float px1 = pr.x + pr.z * 0.5f, py1 = pr.y + pr.w * 0.5f;
            const float parea = (px1 - px0) * (py1 - py0);

            // recompute this prior's PRE-fixup assignment (identical ops/order)
            float bestv = -1.0f;
            int bi = 0;
            for (int o3 = 0; o3 < NO; ++o3) {
                const float* tp = &s_tr[img * TRS + o3 * 5];
                const float tx0 = tp[0], ty0 = tp[1], tx1 = tp[2], ty1 = tp[3];
                const float ta = (tx1 - tx0) * (ty1 - ty0);
                float lx = fmaxf(tx0, px0), ly = fmaxf(ty0, py0);
                float rx = fminf(tx1, px1), ry = fminf(ty1, py1);
                float w = fmaxf(rx - lx, 0.0f);
                float h = fmaxf(ry - ly, 0.0f);
                float inter = w * h;
                float iou = inter * fast_rcp(ta + parea - inter);
                if (iou > bestv) { bestv = iou; bi = o3; }
            }
            const int conf_old = (bestv >= 0.5f)
                               ? ((int)s_tr[img * TRS + bi * 5 + 4] + 1) : 0;
            const int conf_new = (int)s_tr[img * TRS + o * 5 + 4] + 1;

            const float2 cd = conf_data[(size_t)img * NP + bp];
            const float4 ld = loc_data[(size_t)img * NP + bp];

            dlc += focal_term(cd, conf_new) - focal_term(cd, conf_old);
            const float* tn_ = &s_tr[img * TRS + o * 5];
            float sl_new = sl1_term(make_float4(tn_[0], tn_[1], tn_[2], tn_[3]), pr, ld);
            float sl_old = 0.0f;
            if (conf_old > 0) {
                const float* to_ = &s_tr[img * TRS + bi * 5];
                sl_old = sl1_term(make_float4(to_[0], to_[1], to_[2], to_[3]), pr, ld);
            }
            dll += sl_new - sl_old;
            dnp += (conf_old == 0) ? 1 : 0;
        }
    }

    // final reduction: 1024 partials + this thread's deltas
    double ll = (double)dll, lc = (double)dlc;
    unsigned int np = (unsigned int)dnp;
    for (int i = tid; i < NBLK1; i += 256) {
        const float2 v = part_loss[i];
        ll += (double)v.x;
        lc += (double)v.y;
        np += part_np[i];
    }
#pragma unroll
    for (int s = 32; s > 0; s >>= 1) {
        ll += __shfl_xor(ll, s, 64);
        lc += __shfl_xor(lc, s, 64);
        np += __shfl_xor(np, s, 64);
    }
    __shared__ double r_ll[4], r_lc[4];
    __shared__ unsigned int r_np[4];
    const int wid = tid >> 6;
    if ((tid & 63) == 0) { r_ll[wid] = ll; r_lc[wid] = lc; r_np[wid] = np; }
    __syncthreads();
    if (tid == 0) {
        double tl = 0.0, tc = 0.0;
        unsigned int tn = 0;
        for (int w = 0; w < 4; ++w) { tl += r_ll[w]; tc += r_lc[w]; tn += r_np[w]; }
        const double npd = (tn > 0u) ? (double)tn : 1.0;
        out[0] = (float)(tl / npd);
        out[1] = (float)(tc / npd);
    }
}

extern "C" void kernel_launch(void* const* d_in, const int* in_sizes, int n_in,
                              void* d_out, int out_size, void* d_ws, size_t ws_size,
                              hipStream_t stream) {
    const float4* loc_data  = (const float4*)d_in[0];
    const float2* conf_data = (const float2*)d_in[1];
    const float4* priors    = (const float4*)d_in[2];
    const float*  bbox      = (const float*)d_in[3];
    float* out = (float*)d_out;

    unsigned long long* pb_keys = (unsigned long long*)((char*)d_ws + KEY_OFF);
    float2* part_loss = (float2*)((char*)d_ws + PL_OFF);
    unsigned int* part_np = (unsigned int*)((char*)d_ws + PN_OFF);

    match_loss_kernel<<<NBLK1, 256, 0, stream>>>(loc_data, conf_data, priors, bbox,
                                                 pb_keys, part_loss, part_np);
    epilogue_kernel<<<1, 256, 0, stream>>>(loc_data, conf_data, priors, bbox,
                                           pb_keys, part_loss, part_np, out);
}

// Round 14
// 208.337 us; speedup vs baseline: 1.3435x; 1.3435x over previous
//
#include <hip/hip_runtime.h>

// MultiBoxLoss, 2-dispatch pipeline.
// R9 -> R10: (a) REVERT the 4-prior register tile (VGPR 140 -> occupancy
// 11% -> match 135us; R7 structure = 91us @ VGPR 112, occ 20%). (b) fast-math
// the divergent sl1 path (IEEE div+logf ~90 instr -> rcp+v_log ~22; P(wave
// has a positive lane) ~ 96% so the fat path ran ~every wave-iteration) and
// sigmoid-form focal (4 -> 3 transcendentals). (c) epilogue corrections
// parallelized over all 256 threads (2560 (img,o) pairs, 10/thread) --
// R9 residual implies the 128-lane serial version cost ~50-60us.
//
//   K1 match_loss: per (b,p): 20 IoUs once -> pre-fixup conf -> focal+sl1+npos
//                  block-reduced into part[blockIdx]; per-truth best key
//                  (iou_bits<<32|~p) block-reduced -> pb_keys[block][o]
//                  (plain stores, no init kernel, poison-immune).
//   K2 epilogue  : key-reduce 8 chunks/image -> best prior per truth; dedup
//                  (last-wins); delta-correct focal/sl1/npos for <=20
//                  overridden priors/image; reduce 1024 partials -> out[0..1].
//
// match and epilogue share the SAME inline helpers (focal_term / sl1_term /
// IoU expression) so pre-fixup decisions recomputed in the epilogue are
// bit-identical to what match summed.

#define NB 128
#define NP 24564
#define NO 20

#define IPT1 12
#define NCH1 8                       // 8*256*12 = 24576 >= 24564
#define CHUNK (256 * IPT1)           // 3072
#define NBLK1 (NB * NCH1)            // 1024 match blocks

// ws layout (bytes); every region fully overwritten each launch
#define KEY_OFF 0                                   // NBLK1*NO u64 = 163840
#define PL_OFF  ((size_t)NBLK1 * NO * 8)
#define PN_OFF  (PL_OFF + (size_t)NBLK1 * 8)

__device__ __forceinline__ float fast_rcp(float x) {
    return __builtin_amdgcn_rcpf(x);               // v_rcp_f32, ~1-2 ulp
}

// focal = 0.25 * (-log pc) * (1-pc)^2, pc = clamp(softmax[conf], 1e-7, 1-1e-7)
// sigmoid form: conf==0 -> pc = sigmoid(cd.x-cd.y); conf==1 -> sigmoid(cd.y-cd.x)
// 3 transcendentals (exp, rcp, log). Value-only path, tolerance-safe.
__device__ __forceinline__ float focal_term(float2 cd, int conf) {
    float d = cd.x - cd.y;
    float nd = (conf == 0) ? -d : d;
    float t = __expf(nd);                          // e^{nd}, |d| < ~15 here
    float pc = fast_rcp(1.0f + t);                 // sigmoid(-nd)
    pc = fminf(fmaxf(pc, 1e-7f), 1.0f - 1e-7f);
    float om = 1.0f - pc;
    float r = (-0.25f * __logf(pc)) * om * om;
    return (conf > 1) ? 0.0f : r;                  // one_hot(conf>=2,2) == 0
}

// smooth-L1 of encode(matched, prior) vs loc. rcp + v_log fast path (the
// |d|<1 branch is continuous at the boundary; value error ~1e-5 vs 7e-2 tol).
__device__ __forceinline__ float sl1_term(float4 m, float4 pr, float4 ld) {
    float iz = fast_rcp(pr.z), iw = fast_rcp(pr.w);
    float gx = ((m.x + m.z) * 0.5f - pr.x) * iz * 10.0f;   // /(0.1*z)
    float gy = ((m.y + m.w) * 0.5f - pr.y) * iw * 10.0f;
    float gw = __logf((m.z - m.x) * iz) * 5.0f;            // /0.2
    float gh = __logf((m.w - m.y) * iw) * 5.0f;
    float d0 = ld.x - gx, d1 = ld.y - gy, d2 = ld.z - gw, d3 = ld.w - gh;
    float a0 = fabsf(d0), a1 = fabsf(d1), a2 = fabsf(d2), a3 = fabsf(d3);
    float r = (a0 < 1.0f) ? 0.5f * d0 * d0 : a0 - 0.5f;
    r += (a1 < 1.0f) ? 0.5f * d1 * d1 : a1 - 0.5f;
    r += (a2 < 1.0f) ? 0.5f * d2 * d2 : a2 - 0.5f;
    r += (a3 < 1.0f) ? 0.5f * d3 * d3 : a3 - 0.5f;
    return r;
}

__global__ __launch_bounds__(256) void match_loss_kernel(
    const float4* __restrict__ loc_data,   // [B,P,4]
    const float2* __restrict__ conf_data,  // [B,P,2]
    const float4* __restrict__ priors,     // [P,4] center-form
    const float* __restrict__ bbox,        // [B,O,5]
    unsigned long long* __restrict__ pb_keys,   // [NBLK1][NO]
    float2* __restrict__ part_loss,             // [NBLK1]
    unsigned int* __restrict__ part_np)         // [NBLK1]
{
    const int img  = blockIdx.x / NCH1;
    const int base = (blockIdx.x % NCH1) * CHUNK;
    const int tid  = threadIdx.x;
    const size_t iofs = (size_t)img * NP;

    __shared__ float4 s_truth[NO];
    __shared__ float  s_area[NO];
    __shared__ int    s_label[NO];
    __shared__ unsigned long long s_keys[4][NO];

    if (tid < NO) {
        const float* t = bbox + ((size_t)img * NO + tid) * 5;
        float4 tb = make_float4(t[0], t[1], t[2], t[3]);
        s_truth[tid] = tb;
        s_area[tid]  = (tb.z - tb.x) * (tb.w - tb.y);
        s_label[tid] = (int)t[4];
    }
    __syncthreads();

    // per-truth running max (iou, k). strict > keeps smallest k on ties ->
    // smallest p within a thread (first-occurrence, p = base + k*256 + tid).
    float bf[NO];
    int   bk[NO];
#pragma unroll
    for (int o = 0; o < NO; ++o) { bf[o] = -1.0f; bk[o] = 0; }

    float lossl = 0.0f, lossc = 0.0f;
    int np = 0;

    for (int k = 0; k < IPT1; ++k) {
        const int p = base + k * 256 + tid;
        if (p >= NP) break;                   // only tail chunk, monotone in k

        float4 pr = priors[p];                // center-form cx,cy,w,h
        float px0 = pr.x - pr.z * 0.5f, py0 = pr.y - pr.w * 0.5f;
        float px1 = pr.x + pr.z * 0.5f, py1 = pr.y + pr.w * 0.5f;
        float parea = (px1 - px0) * (py1 - py0);

        float bestv = -1.0f;
        int bi = 0;
#pragma unroll
        for (int o = 0; o < NO; ++o) {
            float4 tb = s_truth[o];
            float lx = fmaxf(tb.x, px0), ly = fmaxf(tb.y, py0);
            float rx = fminf(tb.z, px1), ry = fminf(tb.w, py1);
            float w = fmaxf(rx - lx, 0.0f);
            float h = fmaxf(ry - ly, 0.0f);
            float inter = w * h;
            float iou = inter * fast_rcp(s_area[o] + parea - inter);
            if (iou > bf[o]) { bf[o] = iou; bk[o] = k; }       // per-truth max
            if (iou > bestv) { bestv = iou; bi = o; }          // per-prior argmax
        }

        // PRE-fixup losses (epilogue corrects <=20 overridden priors/image)
        const int conf = (bestv >= 0.5f) ? (s_label[bi] + 1) : 0;
        if (conf > 0) {
            np++;
            lossl += sl1_term(s_truth[bi], pr, loc_data[iofs + p]);
        }
        lossc += focal_term(conf_data[iofs + p], conf);
    }

    // per-truth keys: butterfly per wave -> LDS -> block max -> plain store
#pragma unroll
    for (int o = 0; o < NO; ++o) {
        const int p = base + bk[o] * 256 + tid;   // k=0 always valid
        unsigned long long v = ((unsigned long long)__float_as_uint(bf[o]) << 32)
                             | (unsigned long long)(0xFFFFFFFFu - (unsigned)p);
#pragma unroll
        for (int s = 32; s > 0; s >>= 1) {
            unsigned long long u = __shfl_xor(v, s, 64);
            v = (v > u) ? v : u;
        }
        if ((tid & 63) == 0) s_keys[tid >> 6][o] = v;
    }

    // loss block reduce -> private partial slot (no same-address atomics)
#pragma unroll
    for (int s = 32; s > 0; s >>= 1) {
        lossl += __shfl_xor(lossl, s, 64);
        lossc += __shfl_xor(lossc, s, 64);
        np    += __shfl_xor(np, s, 64);
    }
    __shared__ float s_ll[4], s_lc[4];
    __shared__ int s_np4[4];
    const int wid = tid >> 6;
    if ((tid & 63) == 0) { s_ll[wid] = lossl; s_lc[wid] = lossc; s_np4[wid] = np; }
    __syncthreads();

    if (tid < NO) {
        unsigned long long m = s_keys[0][tid];
        for (int w = 1; w < 4; ++w) {
            unsigned long long u = s_keys[w][tid];
            m = (m > u) ? m : u;
        }
        pb_keys[(size_t)blockIdx.x * NO + tid] = m;
    }
    if (tid == 0) {
        float tl = 0.0f, tc = 0.0f;
        int tn = 0;
        for (int w = 0; w < 4; ++w) { tl += s_ll[w]; tc += s_lc[w]; tn += s_np4[w]; }
        part_loss[blockIdx.x] = make_float2(tl, tc);
        part_np[blockIdx.x]   = (unsigned int)tn;
    }
}

// Single block: key reduce + dedup + parallel delta corrections + final sum.
#define TRS 101   // padded truth stride (floats)

__global__ __launch_bounds__(256) void epilogue_kernel(
    const float4* __restrict__ loc_data,
    const float2* __restrict__ conf_data,
    const float4* __restrict__ priors,
    const float* __restrict__ bbox,
    const unsigned long long* __restrict__ pb_keys,
    const float2* __restrict__ part_loss,
    const unsigned int* __restrict__ part_np,
    float* __restrict__ out)
{
    const int tid = threadIdx.x;
    __shared__ float s_tr[NB * TRS];      // 51.7 KB padded truths
    __shared__ int   s_bp[NB][NO];        // 10.2 KB best prior per (img,o)

    for (int i = tid; i < NB * NO * 5; i += 256) {
        const int img = i / (NO * 5), f = i % (NO * 5);
        s_tr[img * TRS + f] = bbox[i];
    }
    // best prior per (img,o): max over the image's 8 chunk keys (coalesced)
    for (int u = tid; u < NB * NO; u += 256) {
        const int img = u / NO, o = u - img * NO;
        unsigned long long m = 0ull;
        for (int c = 0; c < NCH1; ++c) {
            unsigned long long v = pb_keys[((size_t)(img * NCH1 + c)) * NO + o];
            m = (m > v) ? m : v;
        }
        s_bp[img][o] = (int)(0xFFFFFFFFu - (unsigned)(m & 0xFFFFFFFFull));
    }
    __syncthreads();

    // delta corrections: 2560 (img,o) pairs over 256 threads (10 each)
    float dll = 0.0f, dlc = 0.0f;
    int dnp = 0;
#pragma unroll
    for (int r = 0; r < 10; ++r) {
        const int u = tid + 256 * r;               // 2560 = 256*10 exactly
        const int img = u / NO, o = u - (u / NO) * NO;
        const int bp = s_bp[img][o];
        bool win = true;                           // last-wins on duplicates
        for (int o2 = o + 1; o2 < NO; ++o2) win = win && (s_bp[img][o2] != bp);
        if (!win) continue;

        float4 pr = priors[bp];
        const float px0 = pr.x - pr.z * 0.5f, py0 = pr.y - pr.w * 0.5f;
        const float px1 = pr.x + pr.z * 0.5f, py1 = pr.y + pr.w * 0.5f;
        const float parea = (px1 - px0) * (py1 - py0);

        // recompute this prior's PRE-fixup assignment (identical ops/order)
        float bestv = -1.0f;
        int bi = 0;
        for (int o3 = 0; o3 < NO; ++o3) {
            const float* tp = &s_tr[img * TRS + o3 * 5];
            const float tx0 = tp[0], ty0 = tp[1], tx1 = tp[2], ty1 = tp[3];
            const float ta = (tx1 - tx0) * (ty1 - ty0);
            float lx = fmaxf(tx0, px0), ly = fmaxf(ty0, py0);
            float rx = fminf(tx1, px1), ry = fminf(ty1, py1);
            float w = fmaxf(rx - lx, 0.0f);
            float h = fmaxf(ry - ly, 0.0f);
            float inter = w * h;
            float iou = inter * fast_rcp(ta + parea - inter);
            if (iou > bestv) { bestv = iou; bi = o3; }
        }
        const int conf_old = (bestv >= 0.5f)
                           ? ((int)s_tr[img * TRS + bi * 5 + 4] + 1) : 0;
        const int conf_new = (int)s_tr[img * TRS + o * 5 + 4] + 1;

        const float2 cd = conf_data[(size_t)img * NP + bp];
        const float4 ld = loc_data[(size_t)img * NP + bp];

        dlc += focal_term(cd, conf_new) - focal_term(cd, conf_old);
        const float* tn_ = &s_tr[img * TRS + o * 5];
        float sl_new = sl1_term(make_float4(tn_[0], tn_[1], tn_[2], tn_[3]), pr, ld);
        float sl_old = 0.0f;
        if (conf_old > 0) {
            const float* to_ = &s_tr[img * TRS + bi * 5];
            sl_old = sl1_term(make_float4(to_[0], to_[1], to_[2], to_[3]), pr, ld);
        }
        dll += sl_new - sl_old;
        dnp += (conf_old == 0) ? 1 : 0;
    }

    // final reduction: 1024 partials + per-thread deltas
    double ll = (double)dll, lc = (double)dlc;
    unsigned int np = (unsigned int)dnp;
    for (int i = tid; i < NBLK1; i += 256) {
        const float2 v = part_loss[i];
        ll += (double)v.x;
        lc += (double)v.y;
        np += part_np[i];
    }
#pragma unroll
    for (int s = 32; s > 0; s >>= 1) {
        ll += __shfl_xor(ll, s, 64);
        lc += __shfl_xor(lc, s, 64);
        np += __shfl_xor(np, s, 64);
    }
    __shared__ double r_ll[4], r_lc[4];
    __shared__ unsigned int r_np[4];
    const int wid = tid >> 6;
    if ((tid & 63) == 0) { r_ll[wid] = ll; r_lc[wid] = lc; r_np[wid] = np; }
    __syncthreads();
    if (tid == 0) {
        double tl = 0.0, tc = 0.0;
        unsigned int tn = 0;
        for (int w = 0; w < 4; ++w) { tl += r_ll[w]; tc += r_lc[w]; tn += r_np[w]; }
        const double npd = (tn > 0u) ? (double)tn : 1.0;
        out[0] = (float)(tl / npd);
        out[1] = (float)(tc / npd);
    }
}

extern "C" void kernel_launch(void* const* d_in, const int* in_sizes, int n_in,
                              void* d_out, int out_size, void* d_ws, size_t ws_size,
                              hipStream_t stream) {
    const float4* loc_data  = (const float4*)d_in[0];
    const float2* conf_data = (const float2*)d_in[1];
    const float4* priors    = (const float4*)d_in[2];
    const float*  bbox      = (const float*)d_in[3];
    float* out = (float*)d_out;

    unsigned long long* pb_keys = (unsigned long long*)((char*)d_ws + KEY_OFF);
    float2* part_loss = (float2*)((char*)d_ws + PL_OFF);
    unsigned int* part_np = (unsigned int*)((char*)d_ws + PN_OFF);

    match_loss_kernel<<<NBLK1, 256, 0, stream>>>(loc_data, conf_data, priors, bbox,
                                                 pb_keys, part_loss, part_np);
    epilogue_kernel<<<1, 256, 0, stream>>>(loc_data, conf_data, priors, bbox,
                                           pb_keys, part_loss, part_np, out);
}